// Round 3
// baseline (271.898 us; speedup 1.0000x reference)
//
#include <hip/hip_runtime.h>
#include <math.h>

#define NPTS 2048
#define BATCH 16
#define KNN 16
#define HID 128
#define RPB 8          // rows (queries) per block = waves per block
#define CAP 128        // compacted-candidate capacity per wave

// ---------------------------------------------------------------------------
// kNN via threshold selection. One wave per query row. (Unchanged from R1.)
// ---------------------------------------------------------------------------
__global__ __launch_bounds__(512) void knn_kernel(const float* __restrict__ pc,
                                                  int* __restrict__ nbr)
{
    __shared__ __align__(16) float4 pts[NPTS];        // x,y,z,|p|^2  (32 KB)
    __shared__ unsigned ckey[RPB][CAP];               // 4 KB
    __shared__ unsigned cidx[RPB][CAP];               // 4 KB

    const int b = blockIdx.x >> 8;                    // 256 blocks per batch
    const int rblk = blockIdx.x & 255;
    const float* p = pc + (size_t)b * NPTS * 3;

    for (int t = threadIdx.x; t < NPTS; t += 512) {
        float x = p[t * 3 + 0], y = p[t * 3 + 1], z = p[t * 3 + 2];
        pts[t] = make_float4(x, y, z, x * x + y * y + z * z);
    }
    __syncthreads();

    const int w = threadIdx.x >> 6;
    const int lane = threadIdx.x & 63;
    const int i = rblk * RPB + w;                     // query row in batch
    const float4 pi = pts[i];

    unsigned key[32];
    #pragma unroll
    for (int t = 0; t < 32; ++t) {
        float4 c = pts[t * 64 + lane];
        float dot = fmaf(pi.x, c.x, fmaf(pi.y, c.y, pi.z * c.z));
        float d2 = fmaf(-2.0f, dot, pi.w + c.w);
        key[t] = __float_as_uint(d2 + 16.0f);
    }

    unsigned km = 0xFFFFFFFFu;
    #pragma unroll
    for (int t = 0; t < 32; ++t) km = min(km, key[t]);

    unsigned v = km;
    #pragma unroll
    for (int k = 2; k <= 64; k <<= 1) {
        #pragma unroll
        for (int j = k >> 1; j > 0; j >>= 1) {
            unsigned o = (unsigned)__shfl_xor((int)v, j, 64);
            bool up = ((lane & k) == 0);
            bool lower = ((lane & j) == 0);
            unsigned mn = min(v, o), mx = max(v, o);
            v = (up == lower) ? mn : mx;
        }
    }
    const unsigned T0 = (unsigned)__shfl((int)v, 15, 64);

    unsigned base = 0;
    #pragma unroll 1
    for (int t = 0; t < 32; ++t) {
        bool pred = key[t] <= T0;
        unsigned long long mask = __ballot(pred);
        if (mask) {
            unsigned prefix = __builtin_amdgcn_mbcnt_hi(
                (unsigned)(mask >> 32),
                __builtin_amdgcn_mbcnt_lo((unsigned)mask, 0));
            unsigned pos = base + prefix;
            if (pred && pos < CAP) {
                ckey[w][pos] = key[t];
                cidx[w][pos] = (unsigned)(t * 64 + lane);
            }
            base += (unsigned)__popcll(mask);
        }
    }
    __threadfence_block();
    const int m = (int)base;

    int* out = nbr + ((size_t)b * NPTS + i) * KNN;

    if (m <= CAP) {
        unsigned k0 = (lane < m) ? ckey[w][lane] : 0xFFFFFFFFu;
        unsigned k1 = (lane + 64 < m) ? ckey[w][lane + 64] : 0xFFFFFFFFu;
        int r0 = 0, r1 = 0;
        if (m <= 64) {
            #pragma unroll 1
            for (int jj = 0; jj < m; ++jj) {
                unsigned kj = ckey[w][jj];
                r0 += (kj < k0) || (kj == k0 && jj < lane);
            }
        } else {
            #pragma unroll 1
            for (int jj = 0; jj < m; ++jj) {
                unsigned kj = ckey[w][jj];
                r0 += (kj < k0) || (kj == k0 && jj < lane);
                r1 += (kj < k1) || (kj == k1 && jj < lane + 64);
            }
        }
        if (lane < m && r0 < KNN) out[r0] = (int)cidx[w][lane];
        if (lane + 64 < m && r1 < KNN) out[r1] = (int)cidx[w][lane + 64];
    } else {
        unsigned T = 0;
        #pragma unroll 1
        for (int bit = 31; bit >= 0; --bit) {
            unsigned trial = T | (1u << bit);
            int cnt = 0;
            #pragma unroll
            for (int t = 0; t < 32; ++t) cnt += (key[t] < trial);
            #pragma unroll
            for (int off = 32; off; off >>= 1)
                cnt += __shfl_xor(cnt, off, 64);
            if (cnt < KNN) T = trial;
        }
        unsigned bs = 0;
        #pragma unroll 1
        for (int t = 0; t < 32; ++t) {
            bool p1 = key[t] < T;
            unsigned long long mask = __ballot(p1);
            if (mask) {
                unsigned prefix = __builtin_amdgcn_mbcnt_hi(
                    (unsigned)(mask >> 32),
                    __builtin_amdgcn_mbcnt_lo((unsigned)mask, 0));
                if (p1) out[bs + prefix] = t * 64 + lane;
                bs += (unsigned)__popcll(mask);
            }
        }
        #pragma unroll 1
        for (int t = 0; t < 32 && bs < KNN; ++t) {
            bool p2 = key[t] == T;
            unsigned long long mask = __ballot(p2);
            if (mask) {
                unsigned prefix = __builtin_amdgcn_mbcnt_hi(
                    (unsigned)(mask >> 32),
                    __builtin_amdgcn_mbcnt_lo((unsigned)mask, 0));
                unsigned pos = bs + prefix;
                if (p2 && pos < KNN) out[pos] = t * 64 + lane;
                bs += (unsigned)__popcll(mask);
            }
        }
    }
}

// ---------------------------------------------------------------------------
// Layer 1: 3 -> 128, fused gather+matvec+bias+relu. One block per point.
// ---------------------------------------------------------------------------
__global__ __launch_bounds__(128) void layer1_kernel(
    const float* __restrict__ pc, const int* __restrict__ nbr,
    const float* __restrict__ W1r, const float* __restrict__ b1,
    const float* __restrict__ W1s, float* __restrict__ x1)
{
    __shared__ float agg[3], xi[3];
    __shared__ float nb[KNN][3];
    const int p = blockIdx.x;                   // global point id
    const int b = p >> 11;
    const float* pcb = pc + ((size_t)b << 11) * 3;
    const int h = threadIdx.x;
    if (h < KNN) {
        int j = nbr[(size_t)p * KNN + h];
        nb[h][0] = pcb[j * 3 + 0];
        nb[h][1] = pcb[j * 3 + 1];
        nb[h][2] = pcb[j * 3 + 2];
    }
    if (h >= KNN && h < KNN + 3) {
        int c = h - KNN;
        xi[c] = pc[(size_t)p * 3 + c];
    }
    __syncthreads();
    if (h < 3) {
        float s = 0.f;
        #pragma unroll
        for (int t = 0; t < KNN; ++t) s += nb[t][h];
        agg[h] = s;
    }
    __syncthreads();
    float acc = b1[h];
    #pragma unroll
    for (int c = 0; c < 3; ++c)
        acc += W1r[h * 3 + c] * agg[c] + W1s[h * 3 + c] * xi[c];
    x1[(size_t)p * HID + h] = fmaxf(acc, 0.f);
}

// ---------------------------------------------------------------------------
// Gather-sum, float4-vectorized: thread (p, c4) sums 16 neighbor rows.
// Sum order = nbr array order (deterministic).
// ---------------------------------------------------------------------------
__global__ __launch_bounds__(256) void gather_kernel(
    const float* __restrict__ x, const int* __restrict__ nbr,
    float* __restrict__ agg)
{
    int gid = blockIdx.x * 256 + threadIdx.x;   // < 32768*32
    int p = gid >> 5;
    int c4 = gid & 31;
    int b = p >> 11;
    const float* xb = x + (((size_t)b << 11) * HID);
    const int4* nr4 = (const int4*)(nbr + (size_t)p * KNN);
    int4 n0 = nr4[0], n1 = nr4[1], n2 = nr4[2], n3 = nr4[3];
    float4 s = make_float4(0.f, 0.f, 0.f, 0.f);
    int idx[16] = {n0.x, n0.y, n0.z, n0.w, n1.x, n1.y, n1.z, n1.w,
                   n2.x, n2.y, n2.z, n2.w, n3.x, n3.y, n3.z, n3.w};
    #pragma unroll
    for (int t = 0; t < 16; ++t) {
        float4 v = *(const float4*)&xb[(size_t)idx[t] * HID + c4 * 4];
        s.x += v.x; s.y += v.y; s.z += v.z; s.w += v.w;
    }
    *(float4*)&agg[(size_t)p * HID + c4 * 4] = s;
}

// ---------------------------------------------------------------------------
// GraphConv 128->128, register-tiled GEMM.
// C[32768x128] = [agg|x] @ [Wr;Ws]^T + b.  Block: 32 points x 128 h.
// Threads 256 = m_t(8) x h_t(32); each thread: 4 points x 4 h register tile.
// A chunk (32x128) staged in LDS stride 132 (conflict-free: m_t lanes span
// all 32 banks, h_t lanes broadcast). W streamed from global (L1/L2).
// Each LDS b128 read feeds 16 FMAs (was 4). Safe in-place: block reads its
// own 32 x-rows (chunk 1) before writing them; no cross-block row access.
// ---------------------------------------------------------------------------
template <bool RELU>
__global__ __launch_bounds__(256) void conv_kernel(
    const float* __restrict__ agg, const float* __restrict__ x,
    const float* __restrict__ Wr, const float* __restrict__ bias,
    const float* __restrict__ Ws, float* __restrict__ out)
{
    __shared__ __align__(16) float As[32][132];
    const int p0 = blockIdx.x * 32;
    const int m_t = threadIdx.x & 7;
    const int h_t = threadIdx.x >> 3;           // 0..31
    const int h0 = h_t * 4;

    float acc[4][4];                            // [point i][h j]
    #pragma unroll
    for (int i = 0; i < 4; ++i)
        #pragma unroll
        for (int j = 0; j < 4; ++j) acc[i][j] = 0.f;

    #pragma unroll 1
    for (int ch = 0; ch < 2; ++ch) {
        const float* src = (ch ? x : agg) + (size_t)p0 * HID;
        const float* W = ch ? Ws : Wr;
        if (ch) __syncthreads();                // protect As before overwrite
        #pragma unroll
        for (int it = 0; it < 4; ++it) {
            int idx = it * 256 + threadIdx.x;   // 0..1023 float4s
            int pp = idx >> 5, c4 = idx & 31;
            float4 vv = ((const float4*)src)[pp * 32 + c4];
            *(float4*)&As[pp][c4 * 4] = vv;
        }
        __syncthreads();

        #pragma unroll 4
        for (int k4 = 0; k4 < 32; ++k4) {
            float4 w0 = *(const float4*)&W[(h0 + 0) * HID + k4 * 4];
            float4 w1 = *(const float4*)&W[(h0 + 1) * HID + k4 * 4];
            float4 w2 = *(const float4*)&W[(h0 + 2) * HID + k4 * 4];
            float4 w3 = *(const float4*)&W[(h0 + 3) * HID + k4 * 4];
            #pragma unroll
            for (int i = 0; i < 4; ++i) {
                float4 a = *(const float4*)&As[m_t + 8 * i][k4 * 4];
                acc[i][0] += a.x * w0.x + a.y * w0.y + a.z * w0.z + a.w * w0.w;
                acc[i][1] += a.x * w1.x + a.y * w1.y + a.z * w1.z + a.w * w1.w;
                acc[i][2] += a.x * w2.x + a.y * w2.y + a.z * w2.z + a.w * w2.w;
                acc[i][3] += a.x * w3.x + a.y * w3.y + a.z * w3.z + a.w * w3.w;
            }
        }
    }

    float4 bv = *(const float4*)&bias[h0];
    #pragma unroll
    for (int i = 0; i < 4; ++i) {
        float4 r;
        r.x = acc[i][0] + bv.x;
        r.y = acc[i][1] + bv.y;
        r.z = acc[i][2] + bv.z;
        r.w = acc[i][3] + bv.w;
        if (RELU) {
            r.x = fmaxf(r.x, 0.f); r.y = fmaxf(r.y, 0.f);
            r.z = fmaxf(r.z, 0.f); r.w = fmaxf(r.w, 0.f);
        }
        *(float4*)&out[(size_t)(p0 + m_t + 8 * i) * HID + h0] = r;
    }
}

// ---------------------------------------------------------------------------
extern "C" void kernel_launch(void* const* d_in, const int* in_sizes, int n_in,
                              void* d_out, int out_size, void* d_ws, size_t ws_size,
                              hipStream_t stream)
{
    const float* pc  = (const float*)d_in[0];
    const float* W1r = (const float*)d_in[1];
    const float* b1  = (const float*)d_in[2];
    const float* W1s = (const float*)d_in[3];
    const float* W2r = (const float*)d_in[4];
    const float* b2  = (const float*)d_in[5];
    const float* W2s = (const float*)d_in[6];
    const float* W3r = (const float*)d_in[7];
    const float* b3  = (const float*)d_in[8];
    const float* W3s = (const float*)d_in[9];
    float* out = (float*)d_out;

    char* ws = (char*)d_ws;
    int*   nbr  = (int*)ws;                                   // 2 MB
    float* xbuf = (float*)(ws + (size_t)2 * 1024 * 1024);     // 16.78 MB
    float* aggb = (float*)(ws + (size_t)(2 * 1024 * 1024) + (size_t)BATCH * NPTS * HID * 4);

    const int NPOINTS = BATCH * NPTS;                         // 32768

    knn_kernel<<<NPOINTS / RPB, 512, 0, stream>>>(pc, nbr);
    layer1_kernel<<<NPOINTS, 128, 0, stream>>>(pc, nbr, W1r, b1, W1s, xbuf);

    gather_kernel<<<NPOINTS * 32 / 256, 256, 0, stream>>>(xbuf, nbr, aggb);
    conv_kernel<true><<<NPOINTS / 32, 256, 0, stream>>>(aggb, xbuf, W2r, b2, W2s, xbuf);

    gather_kernel<<<NPOINTS * 32 / 256, 256, 0, stream>>>(xbuf, nbr, aggb);
    conv_kernel<false><<<NPOINTS / 32, 256, 0, stream>>>(aggb, xbuf, W3r, b3, W3s, out);
}